// Round 7
// baseline (37.586 us; speedup 1.0000x reference)
//
#include <hip/hip_runtime.h>

#define HH 512
#define WW 512
#define HWPIX (HH * WW)
#define BPB 64            // blocks per batch
#define NB  32            // batches
#define NT  256
#define ITERS 4           // float4-groups per thread
#define FXS 16777216.0f   // 2^24 fixed-point scale for conf sums

// Per-batch accumulator. All fields have neutral element 0 so a single
// 2KB hipMemsetAsync(0) initializes: bbox mins/maxes are stored ENCODED
// as atomicMax-able values (rmin_e = HH-rmin, rmax_e = rmax+1, etc.).
struct Acc {
    unsigned pa, va;                  // pixel counts
    unsigned long long pc_fx, vc_fx;  // conf sums, 2^24 fixed point (deterministic)
    unsigned rmin_e, rmax_e, cmin_e, cmax_e;
    unsigned pad[6];                  // pad to 64 B (one cache line per batch)
};

__global__ __launch_bounds__(NT)
void mfe_reduce(const float* __restrict__ in, Acc* __restrict__ acc) {
    const int b = blockIdx.y, k = blockIdx.x, tid = threadIdx.x;

    const float4* p0 = (const float4*)(in + (size_t)b * 3 * HWPIX);
    const float4* p1 = p0 + (HWPIX / 4);
    const float4* p2 = p0 + (HWPIX / 2);

    int   cnt = 0;                 // pa | va<<16 (block total <= 4096 each)
    float pc = 0.f, vc = 0.f;
    int   rmin = HH, rmax = -1, cmin = WW, cmax = -1;

    // consecutive lanes -> consecutive float4 (1KB per load instr, coalesced)
    for (int g = k * NT + tid; g < HWPIX / 4; g += BPB * NT) {
        float4 a  = p0[g];
        float4 b4 = p1[g];
        float4 c4 = p2[g];
        const int row     = g >> 7;          // 128 float4 per 512-px row
        const int colbase = (g & 127) << 2;
        unsigned msk = 0u;
        const float* A = (const float*)&a;
        const float* B = (const float*)&b4;
        const float* C = (const float*)&c4;
        #pragma unroll
        for (int j = 0; j < 4; ++j) {
            float l0 = A[j], l1 = B[j], l2 = C[j];
            float m01 = fmaxf(l0, l1);
            float m   = fmaxf(m01, l2);
            float t0 = l0 - m, t1 = l1 - m, t2 = l2 - m;   // t_max == 0
            float tmin = fminf(fminf(t0, t1), t2);
            float tmid = ((t0 + t1) + t2) - tmin;           // mid = sum - min
            float s    = 1.0f + __expf(tmid) + __expf(tmin);
            float conf = __builtin_amdgcn_rcpf(s);          // softmax prob of argmax
            bool isV = l2 > m01;                            // pred==2 (first-index)
            bool isP = (l1 > l0) && !isV;                   // pred==1
            cnt += (int)isP | ((int)isV << 16);
            pc  += isP ? conf : 0.f;
            vc  += isV ? conf : 0.f;
            msk |= (unsigned)isP << j;
        }
        if (msk) {
            rmin = min(rmin, row);
            rmax = max(rmax, row);
            cmin = min(cmin, colbase + (__ffs(msk) - 1));
            cmax = max(cmax, colbase + (31 - __clz(msk)));
        }
    }

    // wave (64-lane) shuffle reduce
    #pragma unroll
    for (int off = 32; off > 0; off >>= 1) {
        cnt += __shfl_down(cnt, off, 64);
        pc  += __shfl_down(pc, off, 64);
        vc  += __shfl_down(vc, off, 64);
        rmin = min(rmin, __shfl_down(rmin, off, 64));
        rmax = max(rmax, __shfl_down(rmax, off, 64));
        cmin = min(cmin, __shfl_down(cmin, off, 64));
        cmax = max(cmax, __shfl_down(cmax, off, 64));
    }

    struct SPart { int cnt; float pc, vc; int rmin, rmax, cmin, cmax; };
    __shared__ SPart sp[NT / 64];
    const int lane = tid & 63, wid = tid >> 6;
    if (lane == 0) sp[wid] = SPart{cnt, pc, vc, rmin, rmax, cmin, cmax};
    __syncthreads();
    if (tid == 0) {
        SPart r = sp[0];
        #pragma unroll
        for (int w = 1; w < NT / 64; ++w) {
            r.cnt += sp[w].cnt;
            r.pc  += sp[w].pc;   r.vc += sp[w].vc;
            r.rmin = min(r.rmin, sp[w].rmin);
            r.rmax = max(r.rmax, sp[w].rmax);
            r.cmin = min(r.cmin, sp[w].cmin);
            r.cmax = max(r.cmax, sp[w].cmax);
        }
        // Deterministic device-scope integer atomics (no fences needed: the
        // reduced values travel IN the atomic; int ops are assoc+comm).
        Acc* A = &acc[b];
        atomicAdd(&A->pa, (unsigned)(r.cnt & 0xFFFF));
        atomicAdd(&A->va, (unsigned)(r.cnt >> 16));
        atomicAdd(&A->pc_fx, (unsigned long long)(r.pc * FXS));
        atomicAdd(&A->vc_fx, (unsigned long long)(r.vc * FXS));
        atomicMax(&A->rmin_e, (unsigned)(HH - r.rmin));   // empty -> 0 (neutral)
        atomicMax(&A->rmax_e, (unsigned)(r.rmax + 1));
        atomicMax(&A->cmin_e, (unsigned)(WW - r.cmin));
        atomicMax(&A->cmax_e, (unsigned)(r.cmax + 1));
    }
}

__global__ __launch_bounds__(64)
void mfe_featurize(const Acc* __restrict__ acc, float* __restrict__ out) {
    const int b = threadIdx.x;
    if (b >= NB) return;
    Acc a = acc[b];
    const float paf = (float)a.pa;
    const float vaf = (float)a.va;
    const float fa  = paf + vaf;                 // fg = plaque + vessel
    const float pc  = (float)a.pc_fx / FXS;
    const float vc  = (float)a.vc_fx / FXS;
    const bool  ne  = (a.rmax_e > 0);            // any plaque
    const float hr  = ne ? (float)((int)a.rmax_e - 1 - (HH - (int)a.rmin_e)) : 0.f;
    const float wr  = ne ? (float)((int)a.cmax_e - 1 - (WW - (int)a.cmin_e)) : 0.f;
    float* o = out + b * 10;
    o[0] = paf / (vaf + 1e-6f);
    o[1] = paf / (fa + 1e-6f);
    o[2] = pc;
    o[3] = hr / (float)HH;
    o[4] = wr / (float)WW;
    o[5] = 2.0f * (hr + wr) / (float)(HH + WW);
    o[6] = vc;
    o[7] = (a.pa > 0) ? (pc / (paf + 1e-6f)) : 0.f;
    o[8] = fa / (float)HWPIX;
    o[9] = paf / (float)HWPIX;
}

extern "C" void kernel_launch(void* const* d_in, const int* in_sizes, int n_in,
                              void* d_out, int out_size, void* d_ws, size_t ws_size,
                              hipStream_t stream) {
    const float* in  = (const float*)d_in[0];
    float*       out = (float*)d_out;
    Acc*         acc = (Acc*)d_ws;

    // ws is poisoned once (0xAA) and never restored between replays: zero the
    // 2KB accumulator block every call (graph-capture-legal async memset).
    hipMemsetAsync(acc, 0, NB * sizeof(Acc), stream);

    dim3 grid(BPB, NB);
    mfe_reduce<<<grid, NT, 0, stream>>>(in, acc);
    mfe_featurize<<<1, 64, 0, stream>>>(acc, out);
}

// Round 8
// 24.207 us; speedup vs baseline: 1.5527x; 1.5527x over previous
//
#include <hip/hip_runtime.h>

#define HH 512
#define WW 512
#define HWPIX (HH * WW)
#define BPB 64            // blocks per batch
#define NB  32            // batches
#define NT  256

struct Partial {
    int   pa, va;          // plaque / vessel counts
    float pc, vc;          // conf-weighted sums
    int   rmin, rmax, cmin, cmax;  // plaque bbox
};

__global__ __launch_bounds__(NT)
void mfe_reduce(const float* __restrict__ in, Partial* __restrict__ part) {
    const int b = blockIdx.y, k = blockIdx.x, tid = threadIdx.x;

    const float4* p0 = (const float4*)(in + (size_t)b * 3 * HWPIX);
    const float4* p1 = p0 + (HWPIX / 4);
    const float4* p2 = p0 + (HWPIX / 2);

    // Block owns float4 range [k*1024, (k+1)*1024) per stream.
    // Chunk c: g = k*1024 + c*256 + tid -> each load instr covers 64
    // CONSECUTIVE float4 per wave (1KB, perfectly coalesced), and all 12
    // loads issue before any compute (~latency hiding via MLP).
    const int g0 = k * 1024 + tid;
    float4 av[4], bv[4], cv[4];
    #pragma unroll
    for (int c = 0; c < 4; ++c) av[c] = p0[g0 + c * 256];
    #pragma unroll
    for (int c = 0; c < 4; ++c) bv[c] = p1[g0 + c * 256];
    #pragma unroll
    for (int c = 0; c < 4; ++c) cv[c] = p2[g0 + c * 256];

    int   cnt = 0;                 // pa | va<<16 (block totals <= 4096)
    float pc = 0.f, vc = 0.f;
    int   rmin = HH, rmax = -1, cmin = WW, cmax = -1;

    #pragma unroll
    for (int c = 0; c < 4; ++c) {
        const int g = g0 + c * 256;
        const int row     = g >> 7;          // 128 float4 per 512-px row
        const int colbase = (g & 127) << 2;
        unsigned msk = 0u;
        const float* A = (const float*)&av[c];
        const float* B = (const float*)&bv[c];
        const float* C = (const float*)&cv[c];
        #pragma unroll
        for (int j = 0; j < 4; ++j) {
            float l0 = A[j], l1 = B[j], l2 = C[j];
            float m01 = fmaxf(l0, l1);
            float m   = fmaxf(m01, l2);
            float t0 = l0 - m, t1 = l1 - m, t2 = l2 - m;   // t_max == 0
            float tmin = fminf(fminf(t0, t1), t2);
            float tmid = ((t0 + t1) + t2) - tmin;           // mid = sum - min
            float s    = 1.0f + __expf(tmid) + __expf(tmin);
            float conf = __builtin_amdgcn_rcpf(s);          // softmax prob of argmax
            bool isV = l2 > m01;                            // pred==2 (first-index)
            bool isP = (l1 > l0) && !isV;                   // pred==1
            cnt += (int)isP | ((int)isV << 16);
            pc  += isP ? conf : 0.f;
            vc  += isV ? conf : 0.f;
            msk |= (unsigned)isP << j;
        }
        if (msk) {
            rmin = min(rmin, row);
            rmax = max(rmax, row);
            cmin = min(cmin, colbase + (__ffs(msk) - 1));
            cmax = max(cmax, colbase + (31 - __clz(msk)));
        }
    }

    // wave (64-lane) shuffle reduce
    #pragma unroll
    for (int off = 32; off > 0; off >>= 1) {
        cnt += __shfl_down(cnt, off, 64);
        pc  += __shfl_down(pc, off, 64);
        vc  += __shfl_down(vc, off, 64);
        rmin = min(rmin, __shfl_down(rmin, off, 64));
        rmax = max(rmax, __shfl_down(rmax, off, 64));
        cmin = min(cmin, __shfl_down(cmin, off, 64));
        cmax = max(cmax, __shfl_down(cmax, off, 64));
    }

    struct SPart { int cnt; float pc, vc; int rmin, rmax, cmin, cmax; };
    __shared__ SPart sp[NT / 64];
    const int lane = tid & 63, wid = tid >> 6;
    if (lane == 0) sp[wid] = SPart{cnt, pc, vc, rmin, rmax, cmin, cmax};
    __syncthreads();
    if (tid == 0) {
        SPart r = sp[0];
        #pragma unroll
        for (int w = 1; w < NT / 64; ++w) {
            r.cnt += sp[w].cnt;
            r.pc  += sp[w].pc;   r.vc += sp[w].vc;
            r.rmin = min(r.rmin, sp[w].rmin);
            r.rmax = max(r.rmax, sp[w].rmax);
            r.cmin = min(r.cmin, sp[w].cmin);
            r.cmax = max(r.cmax, sp[w].cmax);
        }
        part[b * BPB + k] = Partial{r.cnt & 0xFFFF, r.cnt >> 16, r.pc, r.vc,
                                    r.rmin, r.rmax, r.cmin, r.cmax};
    }
}

__global__ __launch_bounds__(64)
void mfe_finalize(const Partial* __restrict__ part, float* __restrict__ out) {
    const int b    = blockIdx.x;
    const int lane = threadIdx.x;
    Partial r = part[b * BPB + lane];
    int pa = r.pa, va = r.va;
    float pc = r.pc, vc = r.vc;
    int rmin = r.rmin, rmax = r.rmax, cmin = r.cmin, cmax = r.cmax;

    #pragma unroll
    for (int off = 32; off > 0; off >>= 1) {
        pa += __shfl_down(pa, off, 64);
        va += __shfl_down(va, off, 64);
        pc += __shfl_down(pc, off, 64);
        vc += __shfl_down(vc, off, 64);
        rmin = min(rmin, __shfl_down(rmin, off, 64));
        rmax = max(rmax, __shfl_down(rmax, off, 64));
        cmin = min(cmin, __shfl_down(cmin, off, 64));
        cmax = max(cmax, __shfl_down(cmax, off, 64));
    }

    if (lane == 0) {
        const float paf = (float)pa;
        const float vaf = (float)va;
        const float fa  = paf + vaf;                  // fg = plaque + vessel
        const bool  ne  = (rmax >= 0);
        const float hr  = ne ? (float)(rmax - rmin) : 0.f;
        const float wr  = ne ? (float)(cmax - cmin) : 0.f;
        float* o = out + b * 10;
        o[0] = paf / (vaf + 1e-6f);
        o[1] = paf / (fa + 1e-6f);
        o[2] = pc;
        o[3] = hr / (float)HH;
        o[4] = wr / (float)WW;
        o[5] = 2.0f * (hr + wr) / (float)(HH + WW);
        o[6] = vc;
        o[7] = (pa > 0) ? (pc / (paf + 1e-6f)) : 0.f;
        o[8] = fa / (float)HWPIX;
        o[9] = paf / (float)HWPIX;
    }
}

extern "C" void kernel_launch(void* const* d_in, const int* in_sizes, int n_in,
                              void* d_out, int out_size, void* d_ws, size_t ws_size,
                              hipStream_t stream) {
    const float* in  = (const float*)d_in[0];
    float*       out = (float*)d_out;
    Partial*     part = (Partial*)d_ws;

    dim3 grid(BPB, NB);
    mfe_reduce<<<grid, NT, 0, stream>>>(in, part);
    mfe_finalize<<<NB, 64, 0, stream>>>(part, out);
}